// Round 1
// baseline (1408.208 us; speedup 1.0000x reference)
//
#include <hip/hip_runtime.h>
#include <hip/hip_bf16.h>
#include <math.h>
#include <stddef.h>

#define BN 131072
#define CN 40
#define NTOT (BN * CN)
#define MASKW (BN / 64)   // 2048 uint64 words per column

// Workspace layout
struct Ws {
    double lossc[CN];          // zeroed each launch
    double acc;                // zeroed each launch
    int    posc[CN];           // zeroed each launch
    // ---- params written by k_params ----
    float drate[CN];
    float majl[CN];
    float minl[CN];
    float w_hard[CN];
    float w_easy[CN];
    int   hardf[CN];
    int   kdrop[CN];
    int   minpos[CN];
    // ---- drop bitmask written by k_select ----
    unsigned long long mask[CN][MASKW];
};

__device__ __forceinline__ float bce_f(float x, float t) {
    // logaddexp(0,x) - x*t  (numerically stable)
    float m = fmaxf(x, 0.0f);
    return m + log1pf(expf(-fabsf(x))) - x * t;
}
__device__ __forceinline__ float g_f(float x, float t) {
    float s = 1.0f / (1.0f + expf(-x));
    return fabsf(s - t);
}

// ---------------------------------------------------------------- kernel 1
__global__ void k_colreduce(const float* __restrict__ pred,
                            const float* __restrict__ tgt,
                            Ws* __restrict__ ws) {
    __shared__ float sl[CN];
    __shared__ int   sp[CN];
    int tid = threadIdx.x;
    if (tid < CN) { sl[tid] = 0.0f; sp[tid] = 0; }
    __syncthreads();
    int stride = gridDim.x * blockDim.x;
    for (int i = blockIdx.x * blockDim.x + tid; i < NTOT; i += stride) {
        int c = i % CN;
        float p = pred[i], t = tgt[i];
        atomicAdd(&sl[c], bce_f(p, t));
        if (t != 0.0f) atomicAdd(&sp[c], 1);
    }
    __syncthreads();
    if (tid < CN) {
        atomicAdd(&ws->lossc[tid], (double)sl[tid]);
        atomicAdd(&ws->posc[tid], sp[tid]);
    }
}

// ---------------------------------------------------------------- kernel 2
__global__ void k_params(const float* __restrict__ hard_rand,
                         const float* __restrict__ pos_prop,
                         Ws* __restrict__ ws) {
    int c = threadIdx.x;
    __shared__ double lns[CN];
    __shared__ double smn, smx;
    if (c < CN) lns[c] = log10(1.0 + ws->lossc[c]);
    __syncthreads();
    if (c == 0) {
        double a = lns[0], b = lns[0];
        for (int i = 1; i < CN; i++) { a = fmin(a, lns[i]); b = fmax(b, lns[i]); }
        smn = a; smx = b;
    }
    __syncthreads();
    if (c < CN) {
        double norm = 5.0 - 10.0 * (lns[c] - smn) / (smx - smn);
        float drate = (float)(1.0 / (1.0 + exp(-norm)));   // BASE_RATE = 0 -> max() no-op
        float Bf = (float)BN;
        float pos_sum = (float)ws->posc[c];
        float neg_sum = Bf - pos_sum;
        float bal_pos = pos_prop[c] * Bf;
        float bal_neg = Bf - bal_pos;
        bool pos_gt = pos_sum > bal_pos;
        bool neg_gt = neg_sum > bal_neg;
        float balance = pos_gt ? bal_pos : (neg_gt ? bal_neg : 0.0f);
        float dnum_f  = pos_gt ? (pos_sum - bal_pos)
                               : (neg_gt ? (neg_sum - bal_neg) : 0.0f);
        int   kdrop   = (int)floorf(dnum_f);
        float majl = pos_gt ? 1.0f : 0.0f;
        float minl = neg_gt ? 1.0f : 0.0f;
        float maj_cnt = (majl == 1.0f) ? pos_sum : neg_sum;
        float min_cnt = (minl == 1.0f) ? pos_sum : neg_sum;
        ws->drate[c]  = drate;
        ws->majl[c]   = majl;
        ws->minl[c]   = minl;
        ws->w_hard[c] = balance / fmaxf(maj_cnt, 1.0f);
        ws->w_easy[c] = (Bf - balance) / fmaxf(min_cnt, 1.0f);
        ws->hardf[c]  = (hard_rand[c] > drate) ? 1 : 0;
        ws->kdrop[c]  = kdrop;
        ws->minpos[c] = (min_cnt > 0.0f) ? 1 : 0;
    }
}

// ---------------------------------------------------------------- kernel 3
// One block per column: radix-select k-th smallest g among majority elements,
// then write a stable (row-ordered ties) drop bitmask.
__global__ __launch_bounds__(1024) void k_select(const float* __restrict__ pred,
                                                 const float* __restrict__ tgt,
                                                 Ws* __restrict__ ws) {
    int c   = blockIdx.x;
    int tid = threadIdx.x;
    int k   = ws->kdrop[c];
    bool easy = (ws->hardf[c] == 0);
    unsigned long long* mrow = ws->mask[c];
    if (k <= 0 || !easy) {
        for (int i = tid; i < MASKW; i += 1024) mrow[i] = 0ull;
        return;
    }
    float majl = ws->majl[c];

    __shared__ unsigned h[256];
    __shared__ unsigned cum[256];
    __shared__ unsigned sh_sel, sh_krem;

    unsigned prefix = 0;
    unsigned krem   = (unsigned)k;

    for (int level = 0; level < 4; ++level) {
        int shift = 24 - 8 * level;
        for (int i = tid; i < 256; i += 1024) h[i] = 0;
        __syncthreads();
        for (int b = tid; b < BN; b += 1024) {
            float t = tgt[b * CN + c];
            if (t == majl) {
                unsigned bits = __float_as_uint(g_f(pred[b * CN + c], t));
                bool ok = (level == 0) || ((bits >> (shift + 8)) == prefix);
                if (ok) atomicAdd(&h[(bits >> shift) & 0xFFu], 1u);
            }
        }
        __syncthreads();
        // inclusive scan of h -> cum
        if (tid < 256) cum[tid] = h[tid];
        __syncthreads();
        for (int off = 1; off < 256; off <<= 1) {
            unsigned v = 0;
            if (tid < 256 && tid >= off) v = cum[tid - off];
            __syncthreads();
            if (tid < 256 && tid >= off) cum[tid] += v;
            __syncthreads();
        }
        if (tid < 256) {
            unsigned prev = (tid == 0) ? 0u : cum[tid - 1];
            if (cum[tid] >= krem && prev < krem) {
                sh_sel  = (unsigned)tid;
                sh_krem = krem - prev;
            }
        }
        __syncthreads();
        prefix = (prefix << 8) | sh_sel;
        krem   = sh_krem;
        __syncthreads();
    }

    unsigned T    = prefix;       // bit pattern of k-th smallest g
    unsigned need = krem;         // #elements equal to T to drop (row-ordered)

    __shared__ unsigned wcnt[16];
    unsigned base = 0;
    int lane = tid & 63, wid = tid >> 6;
    for (int chunk = 0; chunk < BN / 1024; ++chunk) {
        int b = chunk * 1024 + tid;
        float t = tgt[b * CN + c];
        bool ismaj = (t == majl);
        unsigned bits = 0xFFFFFFFFu;
        if (ismaj) bits = __float_as_uint(g_f(pred[b * CN + c], t));
        bool lt = ismaj && (bits < T);
        bool eq = ismaj && (bits == T);
        unsigned long long bal = __ballot(eq);
        if (lane == 0) wcnt[wid] = (unsigned)__popcll(bal);
        __syncthreads();
        unsigned woff = 0, tot = 0;
        for (int w = 0; w < 16; ++w) {
            unsigned v = wcnt[w];
            if (w < wid) woff += v;
            tot += v;
        }
        unsigned long long lanemask = (lane == 0) ? 0ull : ((~0ull) >> (64 - lane));
        unsigned myrank = base + woff + (unsigned)__popcll(bal & lanemask);
        bool dropped = lt || (eq && myrank < need);
        unsigned long long bd = __ballot(dropped);
        if (lane == 0) mrow[chunk * 16 + wid] = bd;
        base += tot;
        __syncthreads();
    }
}

// ---------------------------------------------------------------- kernel 4
__global__ void k_final(const float* __restrict__ pred,
                        const float* __restrict__ tgt,
                        const float* __restrict__ rnd,
                        Ws* __restrict__ ws) {
    __shared__ double sdata[256];
    double acc = 0.0;
    int stride = gridDim.x * blockDim.x;
    for (int i = blockIdx.x * blockDim.x + threadIdx.x; i < NTOT; i += stride) {
        int b = i / CN;
        int c = i - b * CN;
        float p = pred[i], t = tgt[i], r = rnd[i];
        float bce = bce_f(p, t);
        float g   = g_f(p, t);
        float w;
        if (ws->hardf[c]) {
            w = (t == ws->majl[c]) ? ws->w_hard[c] : 1.0f;
        } else {
            bool dropped = (ws->mask[c][b >> 6] >> (b & 63)) & 1ull;
            if (dropped) w = 0.0f;
            else w = ((t == ws->minl[c]) && ws->minpos[c]) ? ws->w_easy[c] : 1.0f;
        }
        if ((g >= 0.8f) && (g < 1.000001f) && (r > ws->drate[c])) w = 0.0f;
        acc += (double)(bce * w);
    }
    sdata[threadIdx.x] = acc;
    __syncthreads();
    for (int s = blockDim.x / 2; s > 0; s >>= 1) {
        if (threadIdx.x < s) sdata[threadIdx.x] += sdata[threadIdx.x + s];
        __syncthreads();
    }
    if (threadIdx.x == 0) atomicAdd(&ws->acc, sdata[0]);
}

// ---------------------------------------------------------------- kernel 5
__global__ void k_write(Ws* __restrict__ ws, float* __restrict__ out) {
    out[0] = (float)(ws->acc / (double)NTOT);
}

extern "C" void kernel_launch(void* const* d_in, const int* in_sizes, int n_in,
                              void* d_out, int out_size, void* d_ws, size_t ws_size,
                              hipStream_t stream) {
    const float* pred      = (const float*)d_in[0];
    const float* tgt       = (const float*)d_in[1];
    const float* rnd       = (const float*)d_in[2];
    const float* hard_rand = (const float*)d_in[3];
    const float* pos_prop  = (const float*)d_in[4];
    Ws* ws = (Ws*)d_ws;

    // zero the accumulators (lossc, acc, posc) — everything before `drate`
    hipMemsetAsync(d_ws, 0, offsetof(Ws, drate), stream);

    k_colreduce<<<2048, 256, 0, stream>>>(pred, tgt, ws);
    k_params<<<1, 64, 0, stream>>>(hard_rand, pos_prop, ws);
    k_select<<<CN, 1024, 0, stream>>>(pred, tgt, ws);
    k_final<<<2048, 256, 0, stream>>>(pred, tgt, rnd, ws);
    k_write<<<1, 1, 0, stream>>>(ws, (float*)d_out);
}

// Round 3
// 309.402 us; speedup vs baseline: 4.5514x; 4.5514x over previous
//
#include <hip/hip_runtime.h>
#include <hip/hip_bf16.h>
#include <math.h>
#include <stddef.h>

#define BN 131072
#define CN 40
#define NTOT (BN * CN)
#define MASKW (BN / 64)   // 2048 uint64 words per column

// Workspace layout
struct Ws {
    double lossc[CN];          // zeroed each launch
    double acc;                // zeroed each launch
    int    posc[CN];           // zeroed each launch
    // ---- params written by k_params ----
    float drate[CN];
    float majl[CN];
    float minl[CN];
    float w_hard[CN];
    float w_easy[CN];
    int   hardf[CN];
    int   kdrop[CN];
    int   minpos[CN];
    // ---- drop bitmask written by k_select ----
    unsigned long long mask[CN][MASKW];
    // ---- transposed packed keys (g_bits<<1 | t), written by k_fuse ----
    unsigned keys[CN][BN];
};

__device__ __forceinline__ float bce_f(float x, float t) {
    // logaddexp(0,x) - x*t  (numerically stable)
    float m = fmaxf(x, 0.0f);
    return m + log1pf(expf(-fabsf(x))) - x * t;
}
__device__ __forceinline__ float g_f(float x, float t) {
    float s = 1.0f / (1.0f + expf(-x));
    return fabsf(s - t);
}
__device__ __forceinline__ unsigned masked_key(unsigned key, unsigned majb) {
    return ((key & 1u) == majb) ? (key >> 1) : 0xFFFFFFFFu;
}

// ================================================================ FAST PATH
// ---------------------------------------------------------------- kernel A
// Fused: per-column bce sum + pos count, and LDS-tiled transpose of packed
// keys into ws->keys[c][b]. Block = 640 threads, tile = 128 rows (5120 elems).
__global__ __launch_bounds__(640) void k_fuse(const float* __restrict__ pred,
                                              const float* __restrict__ tgt,
                                              Ws* __restrict__ ws) {
    __shared__ unsigned shk[128 * 41];   // +1 pad kills stride-40 bank conflict
    __shared__ float sl[CN];
    __shared__ int   sp[CN];
    int tid = threadIdx.x;
    if (tid < CN) { sl[tid] = 0.0f; sp[tid] = 0; }
    __syncthreads();

    long tile0 = (long)blockIdx.x * 5120;
    int  c0    = (tid * 4) % 40;         // fixed 4 columns per thread
    float accl[4] = {0, 0, 0, 0};
    int   cntp[4] = {0, 0, 0, 0};

    #pragma unroll
    for (int j = 0; j < 2; ++j) {
        int e = j * 2560 + tid * 4;
        const float4 p = *(const float4*)(pred + tile0 + e);
        const float4 t = *(const float4*)(tgt + tile0 + e);
        int r = e / 40;
        #pragma unroll
        for (int u = 0; u < 4; ++u) {
            float pu = (&p.x)[u], tu = (&t.x)[u];
            accl[u] += bce_f(pu, tu);
            int tb = (tu != 0.0f) ? 1 : 0;
            cntp[u] += tb;
            unsigned gb = __float_as_uint(g_f(pu, tu));
            shk[r * 41 + c0 + u] = (gb << 1) | (unsigned)tb;
        }
    }
    #pragma unroll
    for (int u = 0; u < 4; ++u) {
        atomicAdd(&sl[c0 + u], accl[u]);
        atomicAdd(&sp[c0 + u], cntp[u]);
    }
    __syncthreads();

    // write out transposed: group w (0..4) handles columns w*8..w*8+7
    int w = tid / 128, r = tid % 128;
    int row0 = blockIdx.x * 128;
    #pragma unroll
    for (int cc = 0; cc < 8; ++cc) {
        int c = w * 8 + cc;
        ws->keys[c][row0 + r] = shk[r * 41 + c];
    }
    if (tid < CN) {
        atomicAdd(&ws->lossc[tid], (double)sl[tid]);
        atomicAdd(&ws->posc[tid], sp[tid]);
    }
}

// ---------------------------------------------------------------- kernel B
__global__ void k_params(const float* __restrict__ hard_rand,
                         const float* __restrict__ pos_prop,
                         Ws* __restrict__ ws) {
    int c = threadIdx.x;
    __shared__ double lns[CN];
    __shared__ double smn, smx;
    if (c < CN) lns[c] = log10(1.0 + ws->lossc[c]);
    __syncthreads();
    if (c == 0) {
        double a = lns[0], b = lns[0];
        for (int i = 1; i < CN; i++) { a = fmin(a, lns[i]); b = fmax(b, lns[i]); }
        smn = a; smx = b;
    }
    __syncthreads();
    if (c < CN) {
        double norm = 5.0 - 10.0 * (lns[c] - smn) / (smx - smn);
        float drate = (float)(1.0 / (1.0 + exp(-norm)));   // BASE_RATE = 0
        float Bf = (float)BN;
        float pos_sum = (float)ws->posc[c];
        float neg_sum = Bf - pos_sum;
        float bal_pos = pos_prop[c] * Bf;
        float bal_neg = Bf - bal_pos;
        bool pos_gt = pos_sum > bal_pos;
        bool neg_gt = neg_sum > bal_neg;
        float balance = pos_gt ? bal_pos : (neg_gt ? bal_neg : 0.0f);
        float dnum_f  = pos_gt ? (pos_sum - bal_pos)
                               : (neg_gt ? (neg_sum - bal_neg) : 0.0f);
        int   kdrop   = (int)floorf(dnum_f);
        float majl = pos_gt ? 1.0f : 0.0f;
        float minl = neg_gt ? 1.0f : 0.0f;
        float maj_cnt = (majl == 1.0f) ? pos_sum : neg_sum;
        float min_cnt = (minl == 1.0f) ? pos_sum : neg_sum;
        ws->drate[c]  = drate;
        ws->majl[c]   = majl;
        ws->minl[c]   = minl;
        ws->w_hard[c] = balance / fmaxf(maj_cnt, 1.0f);
        ws->w_easy[c] = (Bf - balance) / fmaxf(min_cnt, 1.0f);
        ws->hardf[c]  = (hard_rand[c] > drate) ? 1 : 0;
        ws->kdrop[c]  = kdrop;
        ws->minpos[c] = (min_cnt > 0.0f) ? 1 : 0;
    }
}

// ---------------------------------------------------------------- kernel C
// One block per column: radix-select k-th smallest masked key over the
// CONTIGUOUS transposed column (coalesced; L2-resident after 1st pass),
// then a barrier-free mask pass (ballot for <T; tiny LDS list for ==T ties).
__global__ __launch_bounds__(1024) void k_select2(Ws* __restrict__ ws) {
    int c   = blockIdx.x;
    int tid = threadIdx.x;
    int k   = ws->kdrop[c];
    bool easy = (ws->hardf[c] == 0);
    unsigned long long* mrow = ws->mask[c];
    if (k <= 0 || !easy) {
        for (int i = tid; i < MASKW; i += 1024) mrow[i] = 0ull;
        return;
    }
    unsigned majb = (ws->majl[c] != 0.0f) ? 1u : 0u;
    const unsigned* __restrict__ kc = ws->keys[c];

    __shared__ unsigned h[256];
    __shared__ unsigned cum[256];
    __shared__ unsigned sh_sel, sh_krem;

    unsigned prefix = 0;
    unsigned krem   = (unsigned)k;

    for (int level = 0; level < 4; ++level) {
        int shift = 24 - 8 * level;
        for (int i = tid; i < 256; i += 1024) h[i] = 0;
        __syncthreads();
        for (int b = tid; b < BN; b += 4096) {
            unsigned m0 = masked_key(kc[b],          majb);
            unsigned m1 = masked_key(kc[b + 1024],   majb);
            unsigned m2 = masked_key(kc[b + 2048],   majb);
            unsigned m3 = masked_key(kc[b + 3072],   majb);
            if (level == 0 || (m0 >> (shift + 8)) == prefix) atomicAdd(&h[(m0 >> shift) & 0xFFu], 1u);
            if (level == 0 || (m1 >> (shift + 8)) == prefix) atomicAdd(&h[(m1 >> shift) & 0xFFu], 1u);
            if (level == 0 || (m2 >> (shift + 8)) == prefix) atomicAdd(&h[(m2 >> shift) & 0xFFu], 1u);
            if (level == 0 || (m3 >> (shift + 8)) == prefix) atomicAdd(&h[(m3 >> shift) & 0xFFu], 1u);
        }
        __syncthreads();
        if (tid < 256) cum[tid] = h[tid];
        __syncthreads();
        for (int off = 1; off < 256; off <<= 1) {
            unsigned v = 0;
            if (tid < 256 && tid >= off) v = cum[tid - off];
            __syncthreads();
            if (tid < 256 && tid >= off) cum[tid] += v;
            __syncthreads();
        }
        if (tid < 256) {
            unsigned prev = (tid == 0) ? 0u : cum[tid - 1];
            if (cum[tid] >= krem && prev < krem) {
                sh_sel  = (unsigned)tid;
                sh_krem = krem - prev;
            }
        }
        __syncthreads();
        prefix = (prefix << 8) | sh_sel;
        krem   = sh_krem;
        __syncthreads();
    }

    unsigned T    = prefix;       // bit pattern of k-th smallest masked key
    unsigned need = krem;         // #elements equal to T to drop (row order)

    __shared__ unsigned eqcnt;
    __shared__ int eqlist[4096];
    if (tid == 0) eqcnt = 0;
    __syncthreads();

    int lane = tid & 63, wid = tid >> 6;
    // barrier-free main pass: strict-less bits via ballot, collect ties
    for (int chunk = 0; chunk < BN / 1024; ++chunk) {
        int b = chunk * 1024 + tid;
        unsigned m = masked_key(kc[b], majb);
        bool lt = m < T;
        unsigned long long bd = __ballot(lt);
        if (lane == 0) mrow[chunk * 16 + wid] = bd;
        if (m == T) {
            unsigned idx = atomicAdd(&eqcnt, 1u);
            if (idx < 4096u) eqlist[idx] = b;
        }
    }
    __syncthreads();
    unsigned ec = eqcnt;
    if (ec <= 4096u) {
        // stable rank among ties by row index; drop first `need`
        for (int t = tid; t < (int)ec; t += 1024) {
            int row = eqlist[t];
            unsigned cnt = 0;
            for (int s = 0; s < (int)ec; ++s) cnt += (eqlist[s] < row) ? 1u : 0u;
            if (cnt < need)
                atomicOr(&mrow[row >> 6], 1ull << (row & 63));
        }
    } else {
        // pathological tie count: ordered serial scan over chunks (eq only)
        __shared__ unsigned wcnt[16];
        unsigned base = 0;
        for (int chunk = 0; chunk < BN / 1024; ++chunk) {
            int b = chunk * 1024 + tid;
            unsigned m = masked_key(kc[b], majb);
            bool eq = (m == T);
            unsigned long long bal = __ballot(eq);
            if (lane == 0) wcnt[wid] = (unsigned)__popcll(bal);
            __syncthreads();
            unsigned woff = 0, tot = 0;
            for (int w2 = 0; w2 < 16; ++w2) {
                unsigned v = wcnt[w2];
                if (w2 < wid) woff += v;
                tot += v;
            }
            unsigned long long lm = (lane == 0) ? 0ull : ((~0ull) >> (64 - lane));
            unsigned rk = base + woff + (unsigned)__popcll(bal & lm);
            if (eq && rk < need)
                atomicOr(&mrow[b >> 6], 1ull << (b & 63));
            base += tot;
            __syncthreads();
        }
    }
}

// ---------------------------------------------------------------- kernel D
__global__ __launch_bounds__(640) void k_final2(const float* __restrict__ pred,
                                                const float* __restrict__ tgt,
                                                const float* __restrict__ rnd,
                                                Ws* __restrict__ ws) {
    int tid = threadIdx.x;
    long tile0 = (long)blockIdx.x * 5120;
    int  c0    = (tid * 4) % 40;
    float drate[4], majl[4], minl[4], wh[4], we[4];
    int hf[4], mp[4];
    #pragma unroll
    for (int u = 0; u < 4; ++u) {
        int c = c0 + u;
        drate[u] = ws->drate[c]; majl[u] = ws->majl[c]; minl[u] = ws->minl[c];
        wh[u] = ws->w_hard[c];   we[u] = ws->w_easy[c];
        hf[u] = ws->hardf[c];    mp[u] = ws->minpos[c];
    }
    double acc = 0.0;
    #pragma unroll
    for (int j = 0; j < 2; ++j) {
        long i = tile0 + j * 2560 + tid * 4;
        const float4 p  = *(const float4*)(pred + i);
        const float4 t  = *(const float4*)(tgt + i);
        const float4 rr = *(const float4*)(rnd + i);
        int b = (int)(i / 40);
        int wsh = b >> 6, bit = b & 63;
        #pragma unroll
        for (int u = 0; u < 4; ++u) {
            float pu = (&p.x)[u], tu = (&t.x)[u], ru = (&rr.x)[u];
            float bce = bce_f(pu, tu);
            float g   = g_f(pu, tu);
            float w;
            if (hf[u]) {
                w = (tu == majl[u]) ? wh[u] : 1.0f;
            } else {
                bool dropped = (ws->mask[c0 + u][wsh] >> bit) & 1ull;
                w = dropped ? 0.0f : ((tu == minl[u] && mp[u]) ? we[u] : 1.0f);
            }
            if (g >= 0.8f && g < 1.000001f && ru > drate[u]) w = 0.0f;
            acc += (double)(bce * w);
        }
    }
    __shared__ double sd[640];
    sd[tid] = acc;
    __syncthreads();
    for (int s = 320; s >= 5; s >>= 1) {
        if (tid < s) sd[tid] += sd[tid + s];
        __syncthreads();
    }
    if (tid == 0) {
        double v = sd[0] + sd[1] + sd[2] + sd[3] + sd[4];
        atomicAdd(&ws->acc, v);
    }
}

// ---------------------------------------------------------------- kernel E
__global__ void k_write(Ws* __restrict__ ws, float* __restrict__ out) {
    out[0] = (float)(ws->acc / (double)NTOT);
}

// ================================================================ FALLBACK
// (round-1 proven path, used only if ws_size can't hold the keys array)
__global__ void k_colreduce(const float* __restrict__ pred,
                            const float* __restrict__ tgt,
                            Ws* __restrict__ ws) {
    __shared__ float sl[CN];
    __shared__ int   sp[CN];
    int tid = threadIdx.x;
    if (tid < CN) { sl[tid] = 0.0f; sp[tid] = 0; }
    __syncthreads();
    int stride = gridDim.x * blockDim.x;
    for (int i = blockIdx.x * blockDim.x + tid; i < NTOT; i += stride) {
        int c = i % CN;
        float p = pred[i], t = tgt[i];
        atomicAdd(&sl[c], bce_f(p, t));
        if (t != 0.0f) atomicAdd(&sp[c], 1);
    }
    __syncthreads();
    if (tid < CN) {
        atomicAdd(&ws->lossc[tid], (double)sl[tid]);
        atomicAdd(&ws->posc[tid], sp[tid]);
    }
}

__global__ __launch_bounds__(1024) void k_select(const float* __restrict__ pred,
                                                 const float* __restrict__ tgt,
                                                 Ws* __restrict__ ws) {
    int c   = blockIdx.x;
    int tid = threadIdx.x;
    int k   = ws->kdrop[c];
    bool easy = (ws->hardf[c] == 0);
    unsigned long long* mrow = ws->mask[c];
    if (k <= 0 || !easy) {
        for (int i = tid; i < MASKW; i += 1024) mrow[i] = 0ull;
        return;
    }
    float majl = ws->majl[c];
    __shared__ unsigned h[256];
    __shared__ unsigned cum[256];
    __shared__ unsigned sh_sel, sh_krem;
    unsigned prefix = 0;
    unsigned krem   = (unsigned)k;
    for (int level = 0; level < 4; ++level) {
        int shift = 24 - 8 * level;
        for (int i = tid; i < 256; i += 1024) h[i] = 0;
        __syncthreads();
        for (int b = tid; b < BN; b += 1024) {
            float t = tgt[b * CN + c];
            if (t == majl) {
                unsigned bits = __float_as_uint(g_f(pred[b * CN + c], t));
                bool ok = (level == 0) || ((bits >> (shift + 8)) == prefix);
                if (ok) atomicAdd(&h[(bits >> shift) & 0xFFu], 1u);
            }
        }
        __syncthreads();
        if (tid < 256) cum[tid] = h[tid];
        __syncthreads();
        for (int off = 1; off < 256; off <<= 1) {
            unsigned v = 0;
            if (tid < 256 && tid >= off) v = cum[tid - off];
            __syncthreads();
            if (tid < 256 && tid >= off) cum[tid] += v;
            __syncthreads();
        }
        if (tid < 256) {
            unsigned prev = (tid == 0) ? 0u : cum[tid - 1];
            if (cum[tid] >= krem && prev < krem) {
                sh_sel  = (unsigned)tid;
                sh_krem = krem - prev;
            }
        }
        __syncthreads();
        prefix = (prefix << 8) | sh_sel;
        krem   = sh_krem;
        __syncthreads();
    }
    unsigned T    = prefix;
    unsigned need = krem;
    __shared__ unsigned wcnt[16];
    unsigned base = 0;
    int lane = tid & 63, wid = tid >> 6;
    for (int chunk = 0; chunk < BN / 1024; ++chunk) {
        int b = chunk * 1024 + tid;
        float t = tgt[b * CN + c];
        bool ismaj = (t == majl);
        unsigned bits = 0xFFFFFFFFu;
        if (ismaj) bits = __float_as_uint(g_f(pred[b * CN + c], t));
        bool lt = ismaj && (bits < T);
        bool eq = ismaj && (bits == T);
        unsigned long long bal = __ballot(eq);
        if (lane == 0) wcnt[wid] = (unsigned)__popcll(bal);
        __syncthreads();
        unsigned woff = 0, tot = 0;
        for (int w = 0; w < 16; ++w) {
            unsigned v = wcnt[w];
            if (w < wid) woff += v;
            tot += v;
        }
        unsigned long long lanemask = (lane == 0) ? 0ull : ((~0ull) >> (64 - lane));
        unsigned myrank = base + woff + (unsigned)__popcll(bal & lanemask);
        bool dropped = lt || (eq && myrank < need);
        unsigned long long bd = __ballot(dropped);
        if (lane == 0) mrow[chunk * 16 + wid] = bd;
        base += tot;
        __syncthreads();
    }
}

__global__ void k_final(const float* __restrict__ pred,
                        const float* __restrict__ tgt,
                        const float* __restrict__ rnd,
                        Ws* __restrict__ ws) {
    __shared__ double sdata[256];
    double acc = 0.0;
    int stride = gridDim.x * blockDim.x;
    for (int i = blockIdx.x * blockDim.x + threadIdx.x; i < NTOT; i += stride) {
        int b = i / CN;
        int c = i - b * CN;
        float p = pred[i], t = tgt[i], r = rnd[i];
        float bce = bce_f(p, t);
        float g   = g_f(p, t);
        float w;
        if (ws->hardf[c]) {
            w = (t == ws->majl[c]) ? ws->w_hard[c] : 1.0f;
        } else {
            bool dropped = (ws->mask[c][b >> 6] >> (b & 63)) & 1ull;
            if (dropped) w = 0.0f;
            else w = ((t == ws->minl[c]) && ws->minpos[c]) ? ws->w_easy[c] : 1.0f;
        }
        if ((g >= 0.8f) && (g < 1.000001f) && (r > ws->drate[c])) w = 0.0f;
        acc += (double)(bce * w);
    }
    sdata[threadIdx.x] = acc;
    __syncthreads();
    for (int s = blockDim.x / 2; s > 0; s >>= 1) {
        if (threadIdx.x < s) sdata[threadIdx.x] += sdata[threadIdx.x + s];
        __syncthreads();
    }
    if (threadIdx.x == 0) atomicAdd(&ws->acc, sdata[0]);
}

extern "C" void kernel_launch(void* const* d_in, const int* in_sizes, int n_in,
                              void* d_out, int out_size, void* d_ws, size_t ws_size,
                              hipStream_t stream) {
    const float* pred      = (const float*)d_in[0];
    const float* tgt       = (const float*)d_in[1];
    const float* rnd       = (const float*)d_in[2];
    const float* hard_rand = (const float*)d_in[3];
    const float* pos_prop  = (const float*)d_in[4];
    Ws* ws = (Ws*)d_ws;

    // zero the accumulators (lossc, acc, posc) — everything before `drate`
    hipMemsetAsync(d_ws, 0, offsetof(Ws, drate), stream);

    if (ws_size >= sizeof(Ws)) {
        k_fuse  <<<1024, 640, 0, stream>>>(pred, tgt, ws);
        k_params<<<1, 64, 0, stream>>>(hard_rand, pos_prop, ws);
        k_select2<<<CN, 1024, 0, stream>>>(ws);
        k_final2<<<1024, 640, 0, stream>>>(pred, tgt, rnd, ws);
    } else {
        k_colreduce<<<2048, 256, 0, stream>>>(pred, tgt, ws);
        k_params<<<1, 64, 0, stream>>>(hard_rand, pos_prop, ws);
        k_select<<<CN, 1024, 0, stream>>>(pred, tgt, ws);
        k_final<<<2048, 256, 0, stream>>>(pred, tgt, rnd, ws);
    }
    k_write<<<1, 1, 0, stream>>>(ws, (float*)d_out);
}

// Round 4
// 298.358 us; speedup vs baseline: 4.7199x; 1.0370x over previous
//
#include <hip/hip_runtime.h>
#include <hip/hip_bf16.h>
#include <math.h>
#include <stddef.h>

#define BN 131072
#define CN 40
#define NTOT (BN * CN)
#define MASKW (BN / 64)   // 2048 uint64 words per column
#define NBLK 1024         // k_fuse / k_final2 grid

// Workspace layout. NOTE: mask[] is union'd with the k_fuse partial sums:
// k_fuse writes partials -> k_params reads them -> k_select2 overwrites mask.
struct Ws {
    double acc;                // zeroed each launch (fast path: only this)
    double lossc[CN];          // fallback path only
    int    posc[CN];           // fallback path only
    // ---- params written by k_params ----
    float drate[CN];
    float majl[CN];
    float minl[CN];
    float w_hard[CN];
    float w_easy[CN];
    int   hardf[CN];
    int   kdrop[CN];
    int   minpos[CN];
    // ---- drop bitmask (k_select2) / k_fuse partials (union) ----
    union {
        unsigned long long mask[CN][MASKW];          // 640 KB
        struct { float lpart[CN][NBLK]; int ppart[CN][NBLK]; } parts; // 320 KB
    } u;
    // ---- transposed packed keys (g_bits<<1 | t), written by k_fuse ----
    unsigned keys[CN][BN];
};

__device__ __forceinline__ float bce_f(float x, float t) {
    float m = fmaxf(x, 0.0f);
    return m + log1pf(expf(-fabsf(x))) - x * t;
}
__device__ __forceinline__ float g_f(float x, float t) {
    float s = 1.0f / (1.0f + expf(-x));
    return fabsf(s - t);
}
// shared-expf fused version (one expf for both bce and g)
__device__ __forceinline__ void bce_g(float x, float t, float& bce, float& g) {
    float e   = expf(-fabsf(x));
    bce       = fmaxf(x, 0.0f) + log1pf(e) - x * t;
    float inv = 1.0f / (1.0f + e);
    float s   = (x >= 0.0f) ? inv : e * inv;   // stable sigmoid
    g         = fabsf(s - t);
}
__device__ __forceinline__ unsigned masked_key(unsigned key, unsigned majb) {
    return ((key & 1u) == majb) ? (key >> 1) : 0xFFFFFFFFu;
}

// ================================================================ FAST PATH
// ---------------------------------------------------------------- kernel A
__global__ __launch_bounds__(640) void k_fuse(const float* __restrict__ pred,
                                              const float* __restrict__ tgt,
                                              Ws* __restrict__ ws) {
    __shared__ unsigned shk[128 * 41];   // +1 pad kills stride-40 bank conflict
    __shared__ float sl[CN];
    __shared__ int   sp[CN];
    int tid = threadIdx.x;
    if (tid < CN) { sl[tid] = 0.0f; sp[tid] = 0; }
    __syncthreads();

    long tile0 = (long)blockIdx.x * 5120;
    int  c0    = (tid * 4) % 40;         // fixed 4 columns per thread
    float accl[4] = {0, 0, 0, 0};
    int   cntp[4] = {0, 0, 0, 0};

    #pragma unroll
    for (int j = 0; j < 2; ++j) {
        int e = j * 2560 + tid * 4;
        const float4 p = *(const float4*)(pred + tile0 + e);
        const float4 t = *(const float4*)(tgt + tile0 + e);
        int r = e / 40;
        #pragma unroll
        for (int u = 0; u < 4; ++u) {
            float pu = (&p.x)[u], tu = (&t.x)[u];
            float bce, g;
            bce_g(pu, tu, bce, g);
            accl[u] += bce;
            int tb = (tu != 0.0f) ? 1 : 0;
            cntp[u] += tb;
            shk[r * 41 + c0 + u] = (__float_as_uint(g) << 1) | (unsigned)tb;
        }
    }
    #pragma unroll
    for (int u = 0; u < 4; ++u) {
        atomicAdd(&sl[c0 + u], accl[u]);
        atomicAdd(&sp[c0 + u], cntp[u]);
    }
    __syncthreads();

    // write out transposed: group w (0..4) handles columns w*8..w*8+7
    int w = tid / 128, r = tid % 128;
    int row0 = blockIdx.x * 128;
    #pragma unroll
    for (int cc = 0; cc < 8; ++cc) {
        int c = w * 8 + cc;
        ws->keys[c][row0 + r] = shk[r * 41 + c];
    }
    // per-block partials instead of contended global double atomics
    if (tid < CN) {
        ws->u.parts.lpart[tid][blockIdx.x] = sl[tid];
        ws->u.parts.ppart[tid][blockIdx.x] = sp[tid];
    }
}

// ---------------------------------------------------------------- kernel B
__global__ __launch_bounds__(1024) void k_params(const float* __restrict__ hard_rand,
                                                 const float* __restrict__ pos_prop,
                                                 Ws* __restrict__ ws, int use_part) {
    int tid = threadIdx.x;
    __shared__ double sred[CN][17];
    __shared__ int    spre[CN][17];
    __shared__ double lossv[CN];
    __shared__ int    posv[CN];
    __shared__ double lns[CN];
    __shared__ double smn, smx;
    if (use_part) {
        if (tid < CN * 16) {
            int c = tid >> 4, j = tid & 15;
            double s = 0.0; int p = 0;
            for (int i = j; i < NBLK; i += 16) {
                s += (double)ws->u.parts.lpart[c][i];
                p += ws->u.parts.ppart[c][i];
            }
            sred[c][j] = s; spre[c][j] = p;
        }
        __syncthreads();
        if (tid < CN) {
            double s = 0.0; int p = 0;
            for (int j = 0; j < 16; ++j) { s += sred[tid][j]; p += spre[tid][j]; }
            lossv[tid] = s; posv[tid] = p;
        }
    } else {
        if (tid < CN) { lossv[tid] = ws->lossc[tid]; posv[tid] = ws->posc[tid]; }
    }
    __syncthreads();
    if (tid < CN) lns[tid] = log10(1.0 + lossv[tid]);
    __syncthreads();
    if (tid == 0) {
        double a = lns[0], b = lns[0];
        for (int i = 1; i < CN; i++) { a = fmin(a, lns[i]); b = fmax(b, lns[i]); }
        smn = a; smx = b;
    }
    __syncthreads();
    if (tid < CN) {
        int c = tid;
        double norm = 5.0 - 10.0 * (lns[c] - smn) / (smx - smn);
        float drate = (float)(1.0 / (1.0 + exp(-norm)));   // BASE_RATE = 0
        float Bf = (float)BN;
        float pos_sum = (float)posv[c];
        float neg_sum = Bf - pos_sum;
        float bal_pos = pos_prop[c] * Bf;
        float bal_neg = Bf - bal_pos;
        bool pos_gt = pos_sum > bal_pos;
        bool neg_gt = neg_sum > bal_neg;
        float balance = pos_gt ? bal_pos : (neg_gt ? bal_neg : 0.0f);
        float dnum_f  = pos_gt ? (pos_sum - bal_pos)
                               : (neg_gt ? (neg_sum - bal_neg) : 0.0f);
        int   kdrop   = (int)floorf(dnum_f);
        float majl = pos_gt ? 1.0f : 0.0f;
        float minl = neg_gt ? 1.0f : 0.0f;
        float maj_cnt = (majl == 1.0f) ? pos_sum : neg_sum;
        float min_cnt = (minl == 1.0f) ? pos_sum : neg_sum;
        ws->drate[c]  = drate;
        ws->majl[c]   = majl;
        ws->minl[c]   = minl;
        ws->w_hard[c] = balance / fmaxf(maj_cnt, 1.0f);
        ws->w_easy[c] = (Bf - balance) / fmaxf(min_cnt, 1.0f);
        ws->hardf[c]  = (hard_rand[c] > drate) ? 1 : 0;
        ws->kdrop[c]  = kdrop;
        ws->minpos[c] = (min_cnt > 0.0f) ? 1 : 0;
    }
}

// ---------------------------------------------------------------- kernel C
// One block per column. Radix select with 11/11/8-bit digits (3 passes) over
// the contiguous transposed column; majority-only atomics; then barrier-free
// mask pass (ballot for <T, tiny LDS list for ==T stable ties).
__global__ __launch_bounds__(1024) void k_select2(Ws* __restrict__ ws) {
    int c   = blockIdx.x;
    int tid = threadIdx.x;
    int k   = ws->kdrop[c];
    bool easy = (ws->hardf[c] == 0);
    unsigned long long* mrow = ws->u.mask[c];
    if (k <= 0 || !easy) {
        for (int i = tid; i < MASKW; i += 1024) mrow[i] = 0ull;
        return;
    }
    unsigned majb = (ws->majl[c] != 0.0f) ? 1u : 0u;
    const unsigned* __restrict__ kc = ws->keys[c];

    __shared__ unsigned h[2048];
    __shared__ unsigned c2[1024];
    __shared__ unsigned sh_sel, sh_krem;

    unsigned krem = (unsigned)k;
    unsigned p0, p01;

    // ---- level 0: digit = mk >> 19 (11 bits) ----
    h[tid] = 0; h[tid + 1024] = 0;
    __syncthreads();
    for (int b = tid; b < BN; b += 4096) {
        #pragma unroll
        for (int q = 0; q < 4; ++q) {
            unsigned key = kc[b + q * 1024];
            if ((key & 1u) == majb) atomicAdd(&h[(key >> 1) >> 19], 1u);
        }
    }
    __syncthreads();
    // pair scan over 2048 bins (1024 pair-sums, Hillis-Steele)
    c2[tid] = h[2 * tid] + h[2 * tid + 1];
    __syncthreads();
    for (int off = 1; off < 1024; off <<= 1) {
        unsigned v = 0;
        if (tid >= off) v = c2[tid - off];
        __syncthreads();
        if (tid >= off) c2[tid] += v;
        __syncthreads();
    }
    {
        unsigned prev = (tid == 0) ? 0u : c2[tid - 1];
        if (c2[tid] >= krem && prev < krem) {
            unsigned h0 = h[2 * tid];
            if (prev + h0 >= krem) { sh_sel = 2 * tid;     sh_krem = krem - prev; }
            else                   { sh_sel = 2 * tid + 1; sh_krem = krem - prev - h0; }
        }
    }
    __syncthreads();
    p0 = sh_sel; krem = sh_krem;
    __syncthreads();

    // ---- level 1: filter mk>>19 == p0; digit = (mk>>8) & 0x7FF ----
    h[tid] = 0; h[tid + 1024] = 0;
    __syncthreads();
    for (int b = tid; b < BN; b += 4096) {
        #pragma unroll
        for (int q = 0; q < 4; ++q) {
            unsigned key = kc[b + q * 1024];
            if ((key & 1u) == majb) {
                unsigned mk = key >> 1;
                if ((mk >> 19) == p0) atomicAdd(&h[(mk >> 8) & 0x7FFu], 1u);
            }
        }
    }
    __syncthreads();
    c2[tid] = h[2 * tid] + h[2 * tid + 1];
    __syncthreads();
    for (int off = 1; off < 1024; off <<= 1) {
        unsigned v = 0;
        if (tid >= off) v = c2[tid - off];
        __syncthreads();
        if (tid >= off) c2[tid] += v;
        __syncthreads();
    }
    {
        unsigned prev = (tid == 0) ? 0u : c2[tid - 1];
        if (c2[tid] >= krem && prev < krem) {
            unsigned h0 = h[2 * tid];
            if (prev + h0 >= krem) { sh_sel = 2 * tid;     sh_krem = krem - prev; }
            else                   { sh_sel = 2 * tid + 1; sh_krem = krem - prev - h0; }
        }
    }
    __syncthreads();
    p01 = (p0 << 11) | sh_sel; krem = sh_krem;
    __syncthreads();

    // ---- level 2: filter mk>>8 == p01; digit = mk & 0xFF (256 bins) ----
    if (tid < 256) h[tid] = 0;
    __syncthreads();
    for (int b = tid; b < BN; b += 4096) {
        #pragma unroll
        for (int q = 0; q < 4; ++q) {
            unsigned key = kc[b + q * 1024];
            if ((key & 1u) == majb) {
                unsigned mk = key >> 1;
                if ((mk >> 8) == p01) atomicAdd(&h[mk & 0xFFu], 1u);
            }
        }
    }
    __syncthreads();
    if (tid < 256) c2[tid] = h[tid];
    __syncthreads();
    for (int off = 1; off < 256; off <<= 1) {
        unsigned v = 0;
        if (tid < 256 && tid >= off) v = c2[tid - off];
        __syncthreads();
        if (tid < 256 && tid >= off) c2[tid] += v;
        __syncthreads();
    }
    if (tid < 256) {
        unsigned prev = (tid == 0) ? 0u : c2[tid - 1];
        if (c2[tid] >= krem && prev < krem) { sh_sel = (unsigned)tid; sh_krem = krem - prev; }
    }
    __syncthreads();

    unsigned T    = (p01 << 8) | sh_sel;   // 30-bit threshold (k-th smallest)
    unsigned need = sh_krem;               // #ties (==T) to drop, in row order

    __shared__ unsigned eqcnt;
    __shared__ int eqlist[4096];
    if (tid == 0) eqcnt = 0;
    __syncthreads();

    int lane = tid & 63, wid = tid >> 6;
    // barrier-free main pass: strict-less via ballot, collect ties
    for (int chunk = 0; chunk < BN / 1024; ++chunk) {
        int b = chunk * 1024 + tid;
        unsigned m = masked_key(kc[b], majb);   // sentinel 0xFFFFFFFF > T always
        bool lt = m < T;
        unsigned long long bd = __ballot(lt);
        if (lane == 0) mrow[chunk * 16 + wid] = bd;
        if (m == T) {
            unsigned idx = atomicAdd(&eqcnt, 1u);
            if (idx < 4096u) eqlist[idx] = b;
        }
    }
    __syncthreads();
    unsigned ec = eqcnt;
    if (ec <= 4096u) {
        for (int t = tid; t < (int)ec; t += 1024) {
            int row = eqlist[t];
            unsigned cnt = 0;
            for (int s = 0; s < (int)ec; ++s) cnt += (eqlist[s] < row) ? 1u : 0u;
            if (cnt < need)
                atomicOr(&mrow[row >> 6], 1ull << (row & 63));
        }
    } else {
        // pathological tie count: ordered serial scan (eq only)
        __shared__ unsigned wcnt[16];
        unsigned base = 0;
        for (int chunk = 0; chunk < BN / 1024; ++chunk) {
            int b = chunk * 1024 + tid;
            unsigned m = masked_key(kc[b], majb);
            bool eq = (m == T);
            unsigned long long bal = __ballot(eq);
            if (lane == 0) wcnt[wid] = (unsigned)__popcll(bal);
            __syncthreads();
            unsigned woff = 0, tot = 0;
            for (int w2 = 0; w2 < 16; ++w2) {
                unsigned v = wcnt[w2];
                if (w2 < wid) woff += v;
                tot += v;
            }
            unsigned long long lm = (lane == 0) ? 0ull : ((~0ull) >> (64 - lane));
            unsigned rk = base + woff + (unsigned)__popcll(bal & lm);
            if (eq && rk < need)
                atomicOr(&mrow[b >> 6], 1ull << (b & 63));
            base += tot;
            __syncthreads();
        }
    }
}

// ---------------------------------------------------------------- kernel D
__global__ __launch_bounds__(640) void k_final2(const float* __restrict__ pred,
                                                const float* __restrict__ tgt,
                                                const float* __restrict__ rnd,
                                                Ws* __restrict__ ws) {
    int tid = threadIdx.x;
    long tile0 = (long)blockIdx.x * 5120;
    int  c0    = (tid * 4) % 40;
    float drate[4], majl[4], minl[4], wh[4], we[4];
    int hf[4], mp[4];
    #pragma unroll
    for (int u = 0; u < 4; ++u) {
        int c = c0 + u;
        drate[u] = ws->drate[c]; majl[u] = ws->majl[c]; minl[u] = ws->minl[c];
        wh[u] = ws->w_hard[c];   we[u] = ws->w_easy[c];
        hf[u] = ws->hardf[c];    mp[u] = ws->minpos[c];
    }
    double acc = 0.0;
    #pragma unroll
    for (int j = 0; j < 2; ++j) {
        long i = tile0 + j * 2560 + tid * 4;
        const float4 p  = *(const float4*)(pred + i);
        const float4 t  = *(const float4*)(tgt + i);
        const float4 rr = *(const float4*)(rnd + i);
        int b = (int)(i / 40);
        int wsh = b >> 6, bit = b & 63;
        #pragma unroll
        for (int u = 0; u < 4; ++u) {
            float pu = (&p.x)[u], tu = (&t.x)[u], ru = (&rr.x)[u];
            float bce, g;
            bce_g(pu, tu, bce, g);
            float w;
            if (hf[u]) {
                w = (tu == majl[u]) ? wh[u] : 1.0f;
            } else {
                bool dropped = (ws->u.mask[c0 + u][wsh] >> bit) & 1ull;
                w = dropped ? 0.0f : ((tu == minl[u] && mp[u]) ? we[u] : 1.0f);
            }
            if (g >= 0.8f && g < 1.000001f && ru > drate[u]) w = 0.0f;
            acc += (double)(bce * w);
        }
    }
    __shared__ double sd[640];
    sd[tid] = acc;
    __syncthreads();
    for (int s = 320; s >= 5; s >>= 1) {
        if (tid < s) sd[tid] += sd[tid + s];
        __syncthreads();
    }
    if (tid == 0) {
        double v = sd[0] + sd[1] + sd[2] + sd[3] + sd[4];
        atomicAdd(&ws->acc, v);
    }
}

// ---------------------------------------------------------------- kernel E
__global__ void k_write(Ws* __restrict__ ws, float* __restrict__ out) {
    out[0] = (float)(ws->acc / (double)NTOT);
}

// ================================================================ FALLBACK
// (round-1 proven path, used only if ws_size can't hold Ws)
__global__ void k_colreduce(const float* __restrict__ pred,
                            const float* __restrict__ tgt,
                            Ws* __restrict__ ws) {
    __shared__ float sl[CN];
    __shared__ int   sp[CN];
    int tid = threadIdx.x;
    if (tid < CN) { sl[tid] = 0.0f; sp[tid] = 0; }
    __syncthreads();
    int stride = gridDim.x * blockDim.x;
    for (int i = blockIdx.x * blockDim.x + tid; i < NTOT; i += stride) {
        int c = i % CN;
        float p = pred[i], t = tgt[i];
        atomicAdd(&sl[c], bce_f(p, t));
        if (t != 0.0f) atomicAdd(&sp[c], 1);
    }
    __syncthreads();
    if (tid < CN) {
        atomicAdd(&ws->lossc[tid], (double)sl[tid]);
        atomicAdd(&ws->posc[tid], sp[tid]);
    }
}

__global__ __launch_bounds__(1024) void k_select(const float* __restrict__ pred,
                                                 const float* __restrict__ tgt,
                                                 Ws* __restrict__ ws) {
    int c   = blockIdx.x;
    int tid = threadIdx.x;
    int k   = ws->kdrop[c];
    bool easy = (ws->hardf[c] == 0);
    unsigned long long* mrow = ws->u.mask[c];
    if (k <= 0 || !easy) {
        for (int i = tid; i < MASKW; i += 1024) mrow[i] = 0ull;
        return;
    }
    float majl = ws->majl[c];
    __shared__ unsigned h[256];
    __shared__ unsigned cum[256];
    __shared__ unsigned sh_sel, sh_krem;
    unsigned prefix = 0;
    unsigned krem   = (unsigned)k;
    for (int level = 0; level < 4; ++level) {
        int shift = 24 - 8 * level;
        for (int i = tid; i < 256; i += 1024) h[i] = 0;
        __syncthreads();
        for (int b = tid; b < BN; b += 1024) {
            float t = tgt[b * CN + c];
            if (t == majl) {
                unsigned bits = __float_as_uint(g_f(pred[b * CN + c], t));
                bool ok = (level == 0) || ((bits >> (shift + 8)) == prefix);
                if (ok) atomicAdd(&h[(bits >> shift) & 0xFFu], 1u);
            }
        }
        __syncthreads();
        if (tid < 256) cum[tid] = h[tid];
        __syncthreads();
        for (int off = 1; off < 256; off <<= 1) {
            unsigned v = 0;
            if (tid < 256 && tid >= off) v = cum[tid - off];
            __syncthreads();
            if (tid < 256 && tid >= off) cum[tid] += v;
            __syncthreads();
        }
        if (tid < 256) {
            unsigned prev = (tid == 0) ? 0u : cum[tid - 1];
            if (cum[tid] >= krem && prev < krem) {
                sh_sel  = (unsigned)tid;
                sh_krem = krem - prev;
            }
        }
        __syncthreads();
        prefix = (prefix << 8) | sh_sel;
        krem   = sh_krem;
        __syncthreads();
    }
    unsigned T    = prefix;
    unsigned need = krem;
    __shared__ unsigned wcnt[16];
    unsigned base = 0;
    int lane = tid & 63, wid = tid >> 6;
    for (int chunk = 0; chunk < BN / 1024; ++chunk) {
        int b = chunk * 1024 + tid;
        float t = tgt[b * CN + c];
        bool ismaj = (t == majl);
        unsigned bits = 0xFFFFFFFFu;
        if (ismaj) bits = __float_as_uint(g_f(pred[b * CN + c], t));
        bool lt = ismaj && (bits < T);
        bool eq = ismaj && (bits == T);
        unsigned long long bal = __ballot(eq);
        if (lane == 0) wcnt[wid] = (unsigned)__popcll(bal);
        __syncthreads();
        unsigned woff = 0, tot = 0;
        for (int w = 0; w < 16; ++w) {
            unsigned v = wcnt[w];
            if (w < wid) woff += v;
            tot += v;
        }
        unsigned long long lanemask = (lane == 0) ? 0ull : ((~0ull) >> (64 - lane));
        unsigned myrank = base + woff + (unsigned)__popcll(bal & lanemask);
        bool dropped = lt || (eq && myrank < need);
        unsigned long long bd = __ballot(dropped);
        if (lane == 0) mrow[chunk * 16 + wid] = bd;
        base += tot;
        __syncthreads();
    }
}

__global__ void k_final(const float* __restrict__ pred,
                        const float* __restrict__ tgt,
                        const float* __restrict__ rnd,
                        Ws* __restrict__ ws) {
    __shared__ double sdata[256];
    double acc = 0.0;
    int stride = gridDim.x * blockDim.x;
    for (int i = blockIdx.x * blockDim.x + threadIdx.x; i < NTOT; i += stride) {
        int b = i / CN;
        int c = i - b * CN;
        float p = pred[i], t = tgt[i], r = rnd[i];
        float bce = bce_f(p, t);
        float g   = g_f(p, t);
        float w;
        if (ws->hardf[c]) {
            w = (t == ws->majl[c]) ? ws->w_hard[c] : 1.0f;
        } else {
            bool dropped = (ws->u.mask[c][b >> 6] >> (b & 63)) & 1ull;
            if (dropped) w = 0.0f;
            else w = ((t == ws->minl[c]) && ws->minpos[c]) ? ws->w_easy[c] : 1.0f;
        }
        if ((g >= 0.8f) && (g < 1.000001f) && (r > ws->drate[c])) w = 0.0f;
        acc += (double)(bce * w);
    }
    sdata[threadIdx.x] = acc;
    __syncthreads();
    for (int s = blockDim.x / 2; s > 0; s >>= 1) {
        if (threadIdx.x < s) sdata[threadIdx.x] += sdata[threadIdx.x + s];
        __syncthreads();
    }
    if (threadIdx.x == 0) atomicAdd(&ws->acc, sdata[0]);
}

extern "C" void kernel_launch(void* const* d_in, const int* in_sizes, int n_in,
                              void* d_out, int out_size, void* d_ws, size_t ws_size,
                              hipStream_t stream) {
    const float* pred      = (const float*)d_in[0];
    const float* tgt       = (const float*)d_in[1];
    const float* rnd       = (const float*)d_in[2];
    const float* hard_rand = (const float*)d_in[3];
    const float* pos_prop  = (const float*)d_in[4];
    Ws* ws = (Ws*)d_ws;

    if (ws_size >= sizeof(Ws)) {
        hipMemsetAsync(d_ws, 0, sizeof(double), stream);   // acc only
        k_fuse   <<<NBLK, 640, 0, stream>>>(pred, tgt, ws);
        k_params <<<1, 1024, 0, stream>>>(hard_rand, pos_prop, ws, 1);
        k_select2<<<CN, 1024, 0, stream>>>(ws);
        k_final2 <<<NBLK, 640, 0, stream>>>(pred, tgt, rnd, ws);
    } else {
        hipMemsetAsync(d_ws, 0, offsetof(Ws, drate), stream);
        k_colreduce<<<2048, 256, 0, stream>>>(pred, tgt, ws);
        k_params <<<1, 1024, 0, stream>>>(hard_rand, pos_prop, ws, 0);
        k_select <<<CN, 1024, 0, stream>>>(pred, tgt, ws);
        k_final  <<<2048, 256, 0, stream>>>(pred, tgt, rnd, ws);
    }
    k_write<<<1, 1, 0, stream>>>(ws, (float*)d_out);
}

// Round 5
// 209.211 us; speedup vs baseline: 6.7311x; 1.4261x over previous
//
#include <hip/hip_runtime.h>
#include <hip/hip_bf16.h>
#include <math.h>
#include <stddef.h>

#define BN 131072
#define CN 40
#define NTOT (BN * CN)
#define MASKW (BN / 64)   // 2048 uint64 words per column
#define NBLK 1024         // k_fuse / k_final2 grid
#define NCHUNK 8          // selection chunks per column
#define CROWS (BN / NCHUNK)   // 16384 rows per chunk

// Workspace layout. Zeroed region = [acc .. ghist2] (one memset).
// u.mask is union'd with k_fuse partials: fuse writes parts -> params reads
// -> k_mask overwrites mask.
struct Ws {
    double acc;
    double pad0;                       // keep following arrays 16B-aligned
    unsigned ghist0[CN][4096];         // level-0 hist (digit = mk>>18, <=4064)
    unsigned ghist1[CN][1024];         // level-1 hist (digit = (mk>>8)&0x3FF)
    unsigned ghist2[CN][256];          // level-2 hist (digit = mk&0xFF)
    // ---- not zeroed below ----
    double lossc[CN];                  // fallback path only
    int    posc[CN];                   // fallback path only
    float drate[CN];
    float majl[CN];
    float minl[CN];
    float w_hard[CN];
    float w_easy[CN];
    int   hardf[CN];
    int   kdrop[CN];
    int   minpos[CN];
    union {
        unsigned long long mask[CN][MASKW];                           // 640 KB
        struct { float lpart[CN][NBLK]; int ppart[CN][NBLK]; } parts; // 320 KB
    } u;
    unsigned long long eqmask[CN][MASKW];  // ==T ballot masks (640 KB)
    unsigned keys[CN][BN];                 // transposed packed (g_bits<<1)|t
};

__device__ __forceinline__ float bce_f(float x, float t) {
    float m = fmaxf(x, 0.0f);
    return m + log1pf(expf(-fabsf(x))) - x * t;
}
__device__ __forceinline__ float g_f(float x, float t) {
    float s = 1.0f / (1.0f + expf(-x));
    return fabsf(s - t);
}
// shared-expf fused version (one expf for both bce and g)
__device__ __forceinline__ void bce_g(float x, float t, float& bce, float& g) {
    float e   = expf(-fabsf(x));
    bce       = fmaxf(x, 0.0f) + log1pf(e) - x * t;
    float inv = 1.0f / (1.0f + e);
    float s   = (x >= 0.0f) ? inv : e * inv;   // stable sigmoid
    g         = fabsf(s - t);
}
__device__ __forceinline__ unsigned masked_key(unsigned key, unsigned majb) {
    return ((key & 1u) == majb) ? (key >> 1) : 0xFFFFFFFFu;
}
__device__ __forceinline__ bool col_active(const Ws* ws, int c) {
    return (ws->kdrop[c] > 0) && (ws->hardf[c] == 0);
}

// Block-wide pick: find first bin where cumulative count >= krem.
// 1024 threads, PER bins/thread. out2[0]=bin, out2[1]=krem-prefix(bin).
// 2 barriers total (wave shuffle scans).
template<int PER, int NBINS>
__device__ __forceinline__ void scan_pick(const unsigned* __restrict__ gh,
                                          unsigned krem,
                                          unsigned* wsum /*[16]*/,
                                          unsigned* out2 /*[2]*/) {
    int tid = threadIdx.x, lane = tid & 63, w = tid >> 6;
    unsigned v[PER];
    unsigned s = 0;
    #pragma unroll
    for (int i = 0; i < PER; ++i) {
        int idx = tid * PER + i;
        v[i] = (idx < NBINS) ? gh[idx] : 0u;
        s += v[i];
    }
    unsigned isc = s;
    #pragma unroll
    for (int d = 1; d < 64; d <<= 1) {
        unsigned o = __shfl_up(isc, (unsigned)d, 64);
        if (lane >= d) isc += o;
    }
    if (lane == 63) wsum[w] = isc;
    __syncthreads();
    unsigned wpre = 0;
    #pragma unroll
    for (int j = 0; j < 16; ++j) wpre += (j < w) ? wsum[j] : 0u;
    unsigned inc = wpre + isc, prev = inc - s;
    if (prev < krem && inc >= krem) {
        unsigned cum = prev;
        #pragma unroll
        for (int i = 0; i < PER; ++i) {
            if (cum < krem && cum + v[i] >= krem) {
                out2[0] = (unsigned)(tid * PER + i);
                out2[1] = krem - cum;
            }
            cum += v[i];
        }
    }
    __syncthreads();
}

// ================================================================ FAST PATH
// ---------------------------------------------------------------- kernel A
// Fused: per-column bce sum + pos count + LDS-tiled transpose of packed keys.
// XCD-swizzled tile mapping: XCD x (bid%8) writes rows [x*16384, (x+1)*16384)
// so the selection chunk x reads locally from XCD x's L2.
__global__ __launch_bounds__(640) void k_fuse(const float* __restrict__ pred,
                                              const float* __restrict__ tgt,
                                              Ws* __restrict__ ws) {
    __shared__ unsigned shk[128 * 41];   // +1 pad kills stride-40 bank conflict
    __shared__ float sl[CN];
    __shared__ int   sp[CN];
    int tid = threadIdx.x;
    if (tid < CN) { sl[tid] = 0.0f; sp[tid] = 0; }
    __syncthreads();

    int  tile  = (blockIdx.x & 7) * 128 + (blockIdx.x >> 3);   // XCD swizzle
    long tile0 = (long)tile * 5120;
    int  c0    = (tid * 4) % 40;         // fixed 4 columns per thread
    float accl[4] = {0, 0, 0, 0};
    int   cntp[4] = {0, 0, 0, 0};

    #pragma unroll
    for (int j = 0; j < 2; ++j) {
        int e = j * 2560 + tid * 4;
        const float4 p = *(const float4*)(pred + tile0 + e);
        const float4 t = *(const float4*)(tgt + tile0 + e);
        int r = e / 40;
        #pragma unroll
        for (int u = 0; u < 4; ++u) {
            float pu = (&p.x)[u], tu = (&t.x)[u];
            float bce, g;
            bce_g(pu, tu, bce, g);
            accl[u] += bce;
            int tb = (tu != 0.0f) ? 1 : 0;
            cntp[u] += tb;
            shk[r * 41 + c0 + u] = (__float_as_uint(g) << 1) | (unsigned)tb;
        }
    }
    #pragma unroll
    for (int u = 0; u < 4; ++u) {
        atomicAdd(&sl[c0 + u], accl[u]);
        atomicAdd(&sp[c0 + u], cntp[u]);
    }
    __syncthreads();

    // write transposed: group w (0..4) handles columns w*8..w*8+7
    int w = tid / 128, r = tid % 128;
    int row0 = tile * 128;
    #pragma unroll
    for (int cc = 0; cc < 8; ++cc) {
        int c = w * 8 + cc;
        ws->keys[c][row0 + r] = shk[r * 41 + c];
    }
    if (tid < CN) {
        ws->u.parts.lpart[tid][blockIdx.x] = sl[tid];
        ws->u.parts.ppart[tid][blockIdx.x] = sp[tid];
    }
}

// ---------------------------------------------------------------- kernel B
__global__ __launch_bounds__(1024) void k_params(const float* __restrict__ hard_rand,
                                                 const float* __restrict__ pos_prop,
                                                 Ws* __restrict__ ws, int use_part) {
    int tid = threadIdx.x;
    __shared__ double sred[CN][17];
    __shared__ int    spre[CN][17];
    __shared__ double lossv[CN];
    __shared__ int    posv[CN];
    __shared__ double lns[CN];
    __shared__ double smn, smx;
    if (use_part) {
        if (tid < CN * 16) {
            int c = tid >> 4, j = tid & 15;
            double s = 0.0; int p = 0;
            for (int i = j; i < NBLK; i += 16) {
                s += (double)ws->u.parts.lpart[c][i];
                p += ws->u.parts.ppart[c][i];
            }
            sred[c][j] = s; spre[c][j] = p;
        }
        __syncthreads();
        if (tid < CN) {
            double s = 0.0; int p = 0;
            for (int j = 0; j < 16; ++j) { s += sred[tid][j]; p += spre[tid][j]; }
            lossv[tid] = s; posv[tid] = p;
        }
    } else {
        if (tid < CN) { lossv[tid] = ws->lossc[tid]; posv[tid] = ws->posc[tid]; }
    }
    __syncthreads();
    if (tid < CN) lns[tid] = log10(1.0 + lossv[tid]);
    __syncthreads();
    if (tid == 0) {
        double a = lns[0], b = lns[0];
        for (int i = 1; i < CN; i++) { a = fmin(a, lns[i]); b = fmax(b, lns[i]); }
        smn = a; smx = b;
    }
    __syncthreads();
    if (tid < CN) {
        int c = tid;
        double norm = 5.0 - 10.0 * (lns[c] - smn) / (smx - smn);
        float drate = (float)(1.0 / (1.0 + exp(-norm)));   // BASE_RATE = 0
        float Bf = (float)BN;
        float pos_sum = (float)posv[c];
        float neg_sum = Bf - pos_sum;
        float bal_pos = pos_prop[c] * Bf;
        float bal_neg = Bf - bal_pos;
        bool pos_gt = pos_sum > bal_pos;
        bool neg_gt = neg_sum > bal_neg;
        float balance = pos_gt ? bal_pos : (neg_gt ? bal_neg : 0.0f);
        float dnum_f  = pos_gt ? (pos_sum - bal_pos)
                               : (neg_gt ? (neg_sum - bal_neg) : 0.0f);
        int   kdrop   = (int)floorf(dnum_f);
        float majl = pos_gt ? 1.0f : 0.0f;
        float minl = neg_gt ? 1.0f : 0.0f;
        float maj_cnt = (majl == 1.0f) ? pos_sum : neg_sum;
        float min_cnt = (minl == 1.0f) ? pos_sum : neg_sum;
        ws->drate[c]  = drate;
        ws->majl[c]   = majl;
        ws->minl[c]   = minl;
        ws->w_hard[c] = balance / fmaxf(maj_cnt, 1.0f);
        ws->w_easy[c] = (Bf - balance) / fmaxf(min_cnt, 1.0f);
        ws->hardf[c]  = (hard_rand[c] > drate) ? 1 : 0;
        ws->kdrop[c]  = kdrop;
        ws->minpos[c] = (min_cnt > 0.0f) ? 1 : 0;
    }
}

// ---------------------------------------------------------------- kernel H0
// grid = CN*NCHUNK; block (c, chunk=bid%8). LDS 4096-bin hist of mk>>18 over
// the chunk's majority elements, flushed with one global atomic per bin.
__global__ __launch_bounds__(1024) void k_hist0(Ws* __restrict__ ws) {
    int c = blockIdx.x >> 3, chunk = blockIdx.x & 7;
    if (!col_active(ws, c)) return;
    unsigned majb = (ws->majl[c] != 0.0f) ? 1u : 0u;
    const uint4* __restrict__ kc4 =
        (const uint4*)(ws->keys[c] + chunk * CROWS);
    __shared__ unsigned h[4096];
    int tid = threadIdx.x;
    for (int i = tid; i < 4096; i += 1024) h[i] = 0;
    __syncthreads();
    for (int b4 = tid; b4 < CROWS / 4; b4 += 1024) {
        uint4 kk = kc4[b4];
        unsigned ks[4] = {kk.x, kk.y, kk.z, kk.w};
        #pragma unroll
        for (int q = 0; q < 4; ++q)
            if ((ks[q] & 1u) == majb) atomicAdd(&h[(ks[q] >> 1) >> 18], 1u);
    }
    __syncthreads();
    for (int i = tid; i < 4096; i += 1024)
        if (h[i]) atomicAdd(&ws->ghist0[c][i], h[i]);
}

// ---------------------------------------------------------------- kernel H1
__global__ __launch_bounds__(1024) void k_hist1(Ws* __restrict__ ws) {
    int c = blockIdx.x >> 3, chunk = blockIdx.x & 7;
    if (!col_active(ws, c)) return;
    __shared__ unsigned wsum[16];
    __shared__ unsigned out2[2];
    scan_pick<4, 4096>(ws->ghist0[c], (unsigned)ws->kdrop[c], wsum, out2);
    unsigned p0 = out2[0];
    unsigned majb = (ws->majl[c] != 0.0f) ? 1u : 0u;
    const uint4* __restrict__ kc4 =
        (const uint4*)(ws->keys[c] + chunk * CROWS);
    __shared__ unsigned h[1024];
    int tid = threadIdx.x;
    h[tid] = 0;
    __syncthreads();
    for (int b4 = tid; b4 < CROWS / 4; b4 += 1024) {
        uint4 kk = kc4[b4];
        unsigned ks[4] = {kk.x, kk.y, kk.z, kk.w};
        #pragma unroll
        for (int q = 0; q < 4; ++q)
            if ((ks[q] & 1u) == majb) {
                unsigned mk = ks[q] >> 1;
                if ((mk >> 18) == p0) atomicAdd(&h[(mk >> 8) & 0x3FFu], 1u);
            }
    }
    __syncthreads();
    if (h[tid]) atomicAdd(&ws->ghist1[c][tid], h[tid]);
}

// ---------------------------------------------------------------- kernel H2
__global__ __launch_bounds__(1024) void k_hist2(Ws* __restrict__ ws) {
    int c = blockIdx.x >> 3, chunk = blockIdx.x & 7;
    if (!col_active(ws, c)) return;
    __shared__ unsigned wsum[16];
    __shared__ unsigned out2[2];
    scan_pick<4, 4096>(ws->ghist0[c], (unsigned)ws->kdrop[c], wsum, out2);
    unsigned p0 = out2[0], krem1 = out2[1];
    scan_pick<1, 1024>(ws->ghist1[c], krem1, wsum, out2);
    unsigned pp = (p0 << 10) | out2[0];     // matched top 23 bits
    unsigned majb = (ws->majl[c] != 0.0f) ? 1u : 0u;
    const uint4* __restrict__ kc4 =
        (const uint4*)(ws->keys[c] + chunk * CROWS);
    __shared__ unsigned h[256];
    int tid = threadIdx.x;
    if (tid < 256) h[tid] = 0;
    __syncthreads();
    for (int b4 = tid; b4 < CROWS / 4; b4 += 1024) {
        uint4 kk = kc4[b4];
        unsigned ks[4] = {kk.x, kk.y, kk.z, kk.w};
        #pragma unroll
        for (int q = 0; q < 4; ++q)
            if ((ks[q] & 1u) == majb) {
                unsigned mk = ks[q] >> 1;
                if ((mk >> 8) == pp) atomicAdd(&h[mk & 0xFFu], 1u);
            }
    }
    __syncthreads();
    if (tid < 256 && h[tid]) atomicAdd(&ws->ghist2[c][tid], h[tid]);
}

// ---------------------------------------------------------------- kernel M
// grid = CN*NCHUNK. Derives T in-block (3 cheap scans), then barrier-free
// ballot pass: lt-mask -> u.mask, eq-mask -> eqmask. Inactive cols zeroed.
__global__ __launch_bounds__(1024) void k_mask(Ws* __restrict__ ws) {
    int c = blockIdx.x >> 3, chunk = blockIdx.x & 7;
    int tid = threadIdx.x;
    unsigned long long* mrow = ws->u.mask[c];
    if (!col_active(ws, c)) {
        if (tid < MASKW / NCHUNK) mrow[chunk * (MASKW / NCHUNK) + tid] = 0ull;
        return;
    }
    __shared__ unsigned wsum[16];
    __shared__ unsigned out2[2];
    scan_pick<4, 4096>(ws->ghist0[c], (unsigned)ws->kdrop[c], wsum, out2);
    unsigned p0 = out2[0], krem1 = out2[1];
    scan_pick<1, 1024>(ws->ghist1[c], krem1, wsum, out2);
    unsigned p1 = out2[0], krem2 = out2[1];
    scan_pick<1, 256>(ws->ghist2[c], krem2, wsum, out2);
    unsigned T = (p0 << 18) | (p1 << 8) | out2[0];

    unsigned majb = (ws->majl[c] != 0.0f) ? 1u : 0u;
    const unsigned* __restrict__ kc = ws->keys[c];
    unsigned long long* erow = ws->eqmask[c];
    int lane = tid & 63, w = tid >> 6;
    int base = chunk * CROWS;
    for (int it = 0; it < CROWS / 1024; ++it) {
        int b = base + it * 1024 + tid;
        unsigned m = masked_key(kc[b], majb);   // sentinel > T always
        unsigned long long blt = __ballot(m < T);
        unsigned long long beq = __ballot(m == T);
        if (lane == 0) {
            int word = (base >> 6) + it * 16 + w;
            mrow[word] = blt;
            erow[word] = beq;
        }
    }
}

// ---------------------------------------------------------------- kernel Tie
// grid = CN. Stable tie resolution: prefix-popcount over eqmask words (row
// order), keep lowest bits of the boundary words, OR into mask.
__global__ __launch_bounds__(1024) void k_tie(Ws* __restrict__ ws) {
    int c = blockIdx.x;
    if (!col_active(ws, c)) return;
    __shared__ unsigned wsum[16];
    __shared__ unsigned out2[2];
    scan_pick<4, 4096>(ws->ghist0[c], (unsigned)ws->kdrop[c], wsum, out2);
    unsigned krem1 = out2[1];
    scan_pick<1, 1024>(ws->ghist1[c], krem1, wsum, out2);
    unsigned krem2 = out2[1];
    scan_pick<1, 256>(ws->ghist2[c], krem2, wsum, out2);
    unsigned need = out2[1];          // >=1 by construction

    int tid = threadIdx.x, lane = tid & 63, w = tid >> 6;
    const unsigned long long* erow = ws->eqmask[c];
    unsigned long long* mrow = ws->u.mask[c];
    unsigned long long e0 = erow[2 * tid], e1 = erow[2 * tid + 1];
    unsigned pc0 = (unsigned)__popcll(e0), pc1 = (unsigned)__popcll(e1);
    unsigned cnt = pc0 + pc1;
    unsigned isc = cnt;
    #pragma unroll
    for (int d = 1; d < 64; d <<= 1) {
        unsigned o = __shfl_up(isc, (unsigned)d, 64);
        if (lane >= d) isc += o;
    }
    if (lane == 63) wsum[w] = isc;
    __syncthreads();
    unsigned wpre = 0;
    #pragma unroll
    for (int j = 0; j < 16; ++j) wpre += (j < w) ? wsum[j] : 0u;
    unsigned prev = wpre + isc - cnt;   // eq count before word 2*tid

    #pragma unroll
    for (int half = 0; half < 2; ++half) {
        unsigned long long e = half ? e1 : e0;
        unsigned pc = half ? pc1 : pc0;
        unsigned p  = half ? prev + pc0 : prev;
        if (pc > 0 && p < need) {
            unsigned keep = need - p;
            if (keep > pc) keep = pc;
            unsigned long long sel;
            if (keep == pc) sel = e;
            else {
                sel = 0ull;
                unsigned long long m = e;
                for (unsigned i = 0; i < keep; ++i) {
                    unsigned long long lsb = m & (~m + 1ull);
                    sel |= lsb;
                    m ^= lsb;
                }
            }
            mrow[2 * tid + half] |= sel;
        }
    }
}

// ---------------------------------------------------------------- kernel D
__global__ __launch_bounds__(640) void k_final2(const float* __restrict__ pred,
                                                const float* __restrict__ tgt,
                                                const float* __restrict__ rnd,
                                                Ws* __restrict__ ws) {
    int tid = threadIdx.x;
    long tile0 = (long)blockIdx.x * 5120;
    int  c0    = (tid * 4) % 40;
    float drate[4], majl[4], minl[4], wh[4], we[4];
    int hf[4], mp[4];
    #pragma unroll
    for (int u = 0; u < 4; ++u) {
        int c = c0 + u;
        drate[u] = ws->drate[c]; majl[u] = ws->majl[c]; minl[u] = ws->minl[c];
        wh[u] = ws->w_hard[c];   we[u] = ws->w_easy[c];
        hf[u] = ws->hardf[c];    mp[u] = ws->minpos[c];
    }
    double acc = 0.0;
    #pragma unroll
    for (int j = 0; j < 2; ++j) {
        long i = tile0 + j * 2560 + tid * 4;
        const float4 p  = *(const float4*)(pred + i);
        const float4 t  = *(const float4*)(tgt + i);
        const float4 rr = *(const float4*)(rnd + i);
        int b = (int)(i / 40);
        int wsh = b >> 6, bit = b & 63;
        #pragma unroll
        for (int u = 0; u < 4; ++u) {
            float pu = (&p.x)[u], tu = (&t.x)[u], ru = (&rr.x)[u];
            float bce, g;
            bce_g(pu, tu, bce, g);
            float w;
            if (hf[u]) {
                w = (tu == majl[u]) ? wh[u] : 1.0f;
            } else {
                bool dropped = (ws->u.mask[c0 + u][wsh] >> bit) & 1ull;
                w = dropped ? 0.0f : ((tu == minl[u] && mp[u]) ? we[u] : 1.0f);
            }
            if (g >= 0.8f && g < 1.000001f && ru > drate[u]) w = 0.0f;
            acc += (double)(bce * w);
        }
    }
    __shared__ double sd[640];
    sd[tid] = acc;
    __syncthreads();
    for (int s = 320; s >= 5; s >>= 1) {
        if (tid < s) sd[tid] += sd[tid + s];
        __syncthreads();
    }
    if (tid == 0) {
        double v = sd[0] + sd[1] + sd[2] + sd[3] + sd[4];
        atomicAdd(&ws->acc, v);
    }
}

// ---------------------------------------------------------------- kernel E
__global__ void k_write(Ws* __restrict__ ws, float* __restrict__ out) {
    out[0] = (float)(ws->acc / (double)NTOT);
}

// ================================================================ FALLBACK
__global__ void k_colreduce(const float* __restrict__ pred,
                            const float* __restrict__ tgt,
                            Ws* __restrict__ ws) {
    __shared__ float sl[CN];
    __shared__ int   sp[CN];
    int tid = threadIdx.x;
    if (tid < CN) { sl[tid] = 0.0f; sp[tid] = 0; }
    __syncthreads();
    int stride = gridDim.x * blockDim.x;
    for (int i = blockIdx.x * blockDim.x + tid; i < NTOT; i += stride) {
        int c = i % CN;
        float p = pred[i], t = tgt[i];
        atomicAdd(&sl[c], bce_f(p, t));
        if (t != 0.0f) atomicAdd(&sp[c], 1);
    }
    __syncthreads();
    if (tid < CN) {
        atomicAdd(&ws->lossc[tid], (double)sl[tid]);
        atomicAdd(&ws->posc[tid], sp[tid]);
    }
}

__global__ __launch_bounds__(1024) void k_select(const float* __restrict__ pred,
                                                 const float* __restrict__ tgt,
                                                 Ws* __restrict__ ws) {
    int c   = blockIdx.x;
    int tid = threadIdx.x;
    int k   = ws->kdrop[c];
    bool easy = (ws->hardf[c] == 0);
    unsigned long long* mrow = ws->u.mask[c];
    if (k <= 0 || !easy) {
        for (int i = tid; i < MASKW; i += 1024) mrow[i] = 0ull;
        return;
    }
    float majl = ws->majl[c];
    __shared__ unsigned h[256];
    __shared__ unsigned cum[256];
    __shared__ unsigned sh_sel, sh_krem;
    unsigned prefix = 0;
    unsigned krem   = (unsigned)k;
    for (int level = 0; level < 4; ++level) {
        int shift = 24 - 8 * level;
        for (int i = tid; i < 256; i += 1024) h[i] = 0;
        __syncthreads();
        for (int b = tid; b < BN; b += 1024) {
            float t = tgt[b * CN + c];
            if (t == majl) {
                unsigned bits = __float_as_uint(g_f(pred[b * CN + c], t));
                bool ok = (level == 0) || ((bits >> (shift + 8)) == prefix);
                if (ok) atomicAdd(&h[(bits >> shift) & 0xFFu], 1u);
            }
        }
        __syncthreads();
        if (tid < 256) cum[tid] = h[tid];
        __syncthreads();
        for (int off = 1; off < 256; off <<= 1) {
            unsigned v = 0;
            if (tid < 256 && tid >= off) v = cum[tid - off];
            __syncthreads();
            if (tid < 256 && tid >= off) cum[tid] += v;
            __syncthreads();
        }
        if (tid < 256) {
            unsigned prev = (tid == 0) ? 0u : cum[tid - 1];
            if (cum[tid] >= krem && prev < krem) {
                sh_sel  = (unsigned)tid;
                sh_krem = krem - prev;
            }
        }
        __syncthreads();
        prefix = (prefix << 8) | sh_sel;
        krem   = sh_krem;
        __syncthreads();
    }
    unsigned T    = prefix;
    unsigned need = krem;
    __shared__ unsigned wcnt[16];
    unsigned base = 0;
    int lane = tid & 63, wid = tid >> 6;
    for (int chunk = 0; chunk < BN / 1024; ++chunk) {
        int b = chunk * 1024 + tid;
        float t = tgt[b * CN + c];
        bool ismaj = (t == majl);
        unsigned bits = 0xFFFFFFFFu;
        if (ismaj) bits = __float_as_uint(g_f(pred[b * CN + c], t));
        bool lt = ismaj && (bits < T);
        bool eq = ismaj && (bits == T);
        unsigned long long bal = __ballot(eq);
        if (lane == 0) wcnt[wid] = (unsigned)__popcll(bal);
        __syncthreads();
        unsigned woff = 0, tot = 0;
        for (int w = 0; w < 16; ++w) {
            unsigned v = wcnt[w];
            if (w < wid) woff += v;
            tot += v;
        }
        unsigned long long lanemask = (lane == 0) ? 0ull : ((~0ull) >> (64 - lane));
        unsigned myrank = base + woff + (unsigned)__popcll(bal & lanemask);
        bool dropped = lt || (eq && myrank < need);
        unsigned long long bd = __ballot(dropped);
        if (lane == 0) mrow[chunk * 16 + wid] = bd;
        base += tot;
        __syncthreads();
    }
}

__global__ void k_final(const float* __restrict__ pred,
                        const float* __restrict__ tgt,
                        const float* __restrict__ rnd,
                        Ws* __restrict__ ws) {
    __shared__ double sdata[256];
    double acc = 0.0;
    int stride = gridDim.x * blockDim.x;
    for (int i = blockIdx.x * blockDim.x + threadIdx.x; i < NTOT; i += stride) {
        int b = i / CN;
        int c = i - b * CN;
        float p = pred[i], t = tgt[i], r = rnd[i];
        float bce = bce_f(p, t);
        float g   = g_f(p, t);
        float w;
        if (ws->hardf[c]) {
            w = (t == ws->majl[c]) ? ws->w_hard[c] : 1.0f;
        } else {
            bool dropped = (ws->u.mask[c][b >> 6] >> (b & 63)) & 1ull;
            if (dropped) w = 0.0f;
            else w = ((t == ws->minl[c]) && ws->minpos[c]) ? ws->w_easy[c] : 1.0f;
        }
        if ((g >= 0.8f) && (g < 1.000001f) && (r > ws->drate[c])) w = 0.0f;
        acc += (double)(bce * w);
    }
    sdata[threadIdx.x] = acc;
    __syncthreads();
    for (int s = blockDim.x / 2; s > 0; s >>= 1) {
        if (threadIdx.x < s) sdata[threadIdx.x] += sdata[threadIdx.x + s];
        __syncthreads();
    }
    if (threadIdx.x == 0) atomicAdd(&ws->acc, sdata[0]);
}

extern "C" void kernel_launch(void* const* d_in, const int* in_sizes, int n_in,
                              void* d_out, int out_size, void* d_ws, size_t ws_size,
                              hipStream_t stream) {
    const float* pred      = (const float*)d_in[0];
    const float* tgt       = (const float*)d_in[1];
    const float* rnd       = (const float*)d_in[2];
    const float* hard_rand = (const float*)d_in[3];
    const float* pos_prop  = (const float*)d_in[4];
    Ws* ws = (Ws*)d_ws;

    if (ws_size >= sizeof(Ws)) {
        // zero acc + ghist0/1/2 (contiguous prefix)
        hipMemsetAsync(d_ws, 0, offsetof(Ws, lossc), stream);
        k_fuse  <<<NBLK, 640, 0, stream>>>(pred, tgt, ws);
        k_params<<<1, 1024, 0, stream>>>(hard_rand, pos_prop, ws, 1);
        k_hist0 <<<CN * NCHUNK, 1024, 0, stream>>>(ws);
        k_hist1 <<<CN * NCHUNK, 1024, 0, stream>>>(ws);
        k_hist2 <<<CN * NCHUNK, 1024, 0, stream>>>(ws);
        k_mask  <<<CN * NCHUNK, 1024, 0, stream>>>(ws);
        k_tie   <<<CN, 1024, 0, stream>>>(ws);
        k_final2<<<NBLK, 640, 0, stream>>>(pred, tgt, rnd, ws);
    } else {
        hipMemsetAsync(d_ws, 0, offsetof(Ws, drate), stream);
        k_colreduce<<<2048, 256, 0, stream>>>(pred, tgt, ws);
        k_params<<<1, 1024, 0, stream>>>(hard_rand, pos_prop, ws, 0);
        k_select<<<CN, 1024, 0, stream>>>(pred, tgt, ws);
        k_final <<<2048, 256, 0, stream>>>(pred, tgt, rnd, ws);
    }
    k_write<<<1, 1, 0, stream>>>(ws, (float*)d_out);
}